// Round 16
// baseline (304.833 us; speedup 1.0000x reference)
//
#include <hip/hip_runtime.h>

#define DD 128
#define NHEAD 8
#define DH 16
#define EPS 1e-5f
#define BSH 9                 // bucket width 512 nodes
#define BWIDTH 512
#define NBLK1 256             // pass-1 blocks

typedef __attribute__((ext_vector_type(8))) short bf16x8;   // 8 bf16 = 4 VGPR
typedef __attribute__((ext_vector_type(4))) float f32x4;

// ---------- bf16 helpers (OCP bf16 = f32 upper half, RNE) ----------
__device__ inline unsigned short f2b(float f) {
    unsigned u = __float_as_uint(f);
    u += 0x7fffu + ((u >> 16) & 1);
    return (unsigned short)(u >> 16);
}
__device__ inline unsigned pk2(float lo, float hi) {
    return (unsigned)f2b(lo) | ((unsigned)f2b(hi) << 16);
}
// unpack-accumulate 8 bf16 (uint4 = 16 B) into a[8]
__device__ inline void upacc(uint4 u, float* a) {
    a[0] += __uint_as_float(u.x << 16);
    a[1] += __uint_as_float(u.x & 0xffff0000u);
    a[2] += __uint_as_float(u.y << 16);
    a[3] += __uint_as_float(u.y & 0xffff0000u);
    a[4] += __uint_as_float(u.z << 16);
    a[5] += __uint_as_float(u.z & 0xffff0000u);
    a[6] += __uint_as_float(u.w << 16);
    a[7] += __uint_as_float(u.w & 0xffff0000u);
}

// XOR swizzle for bf16 MFMA panels (row stride 256 B): keeps 16B alignment.
#define SWZB(row, off) ((off) ^ (((row) & 7) << 4))

// ================= h -> bf16 copy =================
__global__ void k_h2b(const float4* __restrict__ h4, ushort4* __restrict__ hb, int n4) {
    int i = blockIdx.x * 256 + threadIdx.x;
    if (i < n4) {
        float4 v = h4[i];
        hb[i] = make_ushort4(f2b(v.x), f2b(v.y), f2b(v.z), f2b(v.w));
    }
}

// ================= pass 1a: per-block bucket histograms =================
__global__ __launch_bounds__(256) void k_p1count(
        const int* __restrict__ gs, const int* __restrict__ gd,
        const int* __restrict__ as_, const int* __restrict__ ad,
        int* __restrict__ blkcnt, int E, int N, int Btot) {
    __shared__ int cnts[512];
    for (int j = threadIdx.x; j < 2 * Btot; j += 256) cnts[j] = 0;
    __syncthreads();
    int E2 = 2 * E;
    for (int i = blockIdx.x * 256 + threadIdx.x; i < E2; i += NBLK1 * 256) {
        int g = (i >= E);
        int e = g ? i - E : i;
        int s = g ? as_[e] : gs[e];
        int d = g ? ad[e] : gd[e];
        int cd = d + g * N, cs = s + g * N;
        atomicAdd(&cnts[cd >> BSH], 1);
        atomicAdd(&cnts[Btot + (cs >> BSH)], 1);
    }
    __syncthreads();
    for (int j = threadIdx.x; j < 2 * Btot; j += 256)
        blkcnt[j * NBLK1 + blockIdx.x] = cnts[j];
}

// ================= 3-stage scan =================
__global__ void k_scan1(const int* __restrict__ cnt, int* __restrict__ outv,
                        int* __restrict__ part, int n) {
    __shared__ int wsums[4];
    int t = threadIdx.x;
    int base = blockIdx.x * 1024 + t * 4;
    int v0 = 0, v1 = 0, v2 = 0, v3 = 0;
    if (base + 3 < n) {
        int4 q = *(const int4*)(cnt + base);
        v0 = q.x; v1 = q.y; v2 = q.z; v3 = q.w;
    } else {
        if (base < n)     v0 = cnt[base];
        if (base + 1 < n) v1 = cnt[base + 1];
        if (base + 2 < n) v2 = cnt[base + 2];
        if (base + 3 < n) v3 = cnt[base + 3];
    }
    int s0 = v0, s1 = s0 + v1, s2 = s1 + v2, s3 = s2 + v3;
    int x = s3;
    int lane = t & 63, w = t >> 6;
    for (int o = 1; o < 64; o <<= 1) { int u = __shfl_up(x, o); if (lane >= o) x += u; }
    if (lane == 63) wsums[w] = x;
    __syncthreads();
    int wo = 0;
    for (int i = 0; i < w; ++i) wo += wsums[i];
    int excl = wo + x - s3;
    if (base < n)     outv[base]     = excl;
    if (base + 1 < n) outv[base + 1] = excl + s0;
    if (base + 2 < n) outv[base + 2] = excl + s1;
    if (base + 3 < n) outv[base + 3] = excl + s2;
    if (t == 255) part[blockIdx.x] = wo + x;
}

__global__ void k_scan2(int* __restrict__ part, int nb) {
    __shared__ int ws[4];
    int t = threadIdx.x;
    int v = (t < nb) ? part[t] : 0;
    int x = v;
    int lane = t & 63, w = t >> 6;
    for (int o = 1; o < 64; o <<= 1) { int u = __shfl_up(x, o); if (lane >= o) x += u; }
    if (lane == 63) ws[w] = x;
    __syncthreads();
    int wo = 0;
    for (int i = 0; i < w; ++i) wo += ws[i];
    if (t < nb) part[t] = wo + x - v;
}

__global__ void k_scan3(int* __restrict__ outv, const int* __restrict__ part, int n, int total) {
    int i = blockIdx.x * blockDim.x + threadIdx.x;
    if (i < n) outv[i] += part[i >> 10];
    if (i == 0) outv[n] = total;
}

// ======== pass 1b: scatter edges into bucket regions (packed: local_d<<16 | src) ========
__global__ __launch_bounds__(256) void k_p1scatter(
        const int* __restrict__ gs, const int* __restrict__ gd,
        const int* __restrict__ as_, const int* __restrict__ ad,
        const int* __restrict__ scn, unsigned* __restrict__ pairs,
        unsigned short* __restrict__ svals, int E, int N, int Btot) {
    __shared__ int cur[512];
    for (int j = threadIdx.x; j < 2 * Btot; j += 256)
        cur[j] = scn[j * NBLK1 + blockIdx.x];
    __syncthreads();
    int E2 = 2 * E;
    for (int i = blockIdx.x * 256 + threadIdx.x; i < E2; i += NBLK1 * 256) {
        int g = (i >= E);
        int e = g ? i - E : i;
        int s = g ? as_[e] : gs[e];
        int d = g ? ad[e] : gd[e];
        int cd = d + g * N, cs = s + g * N;
        int pd = atomicAdd(&cur[cd >> BSH], 1);
        pairs[pd] = ((unsigned)(cd & (BWIDTH - 1)) << 16) | (unsigned)s;
        int ps = atomicAdd(&cur[Btot + (cs >> BSH)], 1);
        svals[ps - E2] = (unsigned short)(cs & (BWIDTH - 1));
    }
}

// ================= pass 2: per-bucket CSR + indeg + norms =================
__global__ __launch_bounds__(256) void k_p2(
        const unsigned* __restrict__ pairs, const unsigned short* __restrict__ svals,
        const int* __restrict__ scn, int* __restrict__ rowptr, int* __restrict__ csr,
        float* __restrict__ indeg, float* __restrict__ norms,
        int E, int N2, int Btot) {
    __shared__ int hist[BWIDTH];
    __shared__ int offs[BWIDTH];
    __shared__ int cur[BWIDTH];
    __shared__ int ws4[4];
    int b = blockIdx.x, t = threadIdx.x;
    int node0 = b << BSH;
    int W = N2 - node0; if (W > BWIDTH) W = BWIDTH;
    int Sd = scn[b * NBLK1], Ed = scn[(b + 1) * NBLK1];
    hist[t] = 0; hist[t + 256] = 0;
    __syncthreads();
    for (int i = Sd + t; i < Ed; i += 256)
        atomicAdd(&hist[pairs[i] >> 16], 1);
    __syncthreads();
    int a0 = hist[2 * t], a1 = hist[2 * t + 1];
    int sum2 = a0 + a1;
    int lane = t & 63, w = t >> 6;
    int x = sum2;
    for (int o = 1; o < 64; o <<= 1) { int u = __shfl_up(x, o); if (lane >= o) x += u; }
    if (lane == 63) ws4[w] = x;
    __syncthreads();
    int wo = 0;
    for (int i = 0; i < w; ++i) wo += ws4[i];
    int excl2 = wo + x - sum2;
    offs[2 * t] = excl2; offs[2 * t + 1] = excl2 + a0;
    cur[t] = 0; cur[t + 256] = 0;
    __syncthreads();
    for (int j = t; j < W; j += 256) {
        rowptr[node0 + j] = Sd + offs[j];
        indeg[node0 + j] = (float)hist[j];
    }
    if (b == 0 && t == 0) rowptr[N2] = 2 * E;
    for (int i = Sd + t; i < Ed; i += 256) {
        unsigned p = pairs[i];
        int l = p >> 16;
        int pos = atomicAdd(&cur[l], 1);
        csr[Sd + offs[l] + pos] = (int)(p & 0xffffu);
    }
    __syncthreads();
    hist[t] = 0; hist[t + 256] = 0;
    __syncthreads();
    int Ss = scn[(Btot + b) * NBLK1] - 2 * E;
    int Es = scn[(Btot + b + 1) * NBLK1] - 2 * E;
    for (int i = Ss + t; i < Es; i += 256)
        atomicAdd(&hist[svals[i]], 1);
    __syncthreads();
    for (int j = t; j < W; j += 256) {
        int od = hist[j];
        norms[node0 + j] = od > 0 ? rsqrtf((float)od) : 0.f;
    }
}

// ======== fused pull stage 1/2: avg (SAGE); 16 lanes/row, uint4 loads ========
__global__ __launch_bounds__(256) void k_pull_avgF(
        const uint4* __restrict__ xb, const int* __restrict__ rowptr,
        const int* __restrict__ csr, const float* __restrict__ norms,
        uint4* __restrict__ outb, float* __restrict__ ssum,
        int N, int shared_in, int doscale) {
    int cd = blockIdx.x * 16 + (threadIdx.x >> 4);
    int lane = threadIdx.x & 15;
    if (cd >= 2 * N) return;
    int gofs = (cd >= N) ? N : 0;
    int base = shared_in ? 0 : gofs;
    int beg = rowptr[cd], end = rowptr[cd + 1];
    float a[8];
    {
        uint4 u = xb[(size_t)(base + cd - gofs) * 16 + lane];   // self term
        a[0] = __uint_as_float(u.x << 16); a[1] = __uint_as_float(u.x & 0xffff0000u);
        a[2] = __uint_as_float(u.y << 16); a[3] = __uint_as_float(u.y & 0xffff0000u);
        a[4] = __uint_as_float(u.z << 16); a[5] = __uint_as_float(u.z & 0xffff0000u);
        a[6] = __uint_as_float(u.w << 16); a[7] = __uint_as_float(u.w & 0xffff0000u);
    }
    float ss = 0.f;
    int e = beg;
    int nb = end - e; if (nb > 16) nb = 16;
    int idx = (lane < nb) ? csr[e + lane] : 0;
    while (nb > 0) {
        int en = e + nb;
        int nbn = end - en; if (nbn > 16) nbn = 16;
        int idxn = (lane < nbn) ? csr[en + lane] : 0;           // prefetch next chunk
        #pragma unroll 8
        for (int d = 0; d < nb; ++d) {
            int s = __shfl(idx, d, 16);
            upacc(xb[(size_t)(base + s) * 16 + lane], a);
            if (doscale) ss += norms[base + s];
        }
        e = en; nb = nbn; idx = idxn;
    }
    float sc = 1.f / (float)(end - beg + 1);
    if (doscale) sc *= norms[cd];
    uint4 o;
    o.x = pk2(a[0] * sc, a[1] * sc); o.y = pk2(a[2] * sc, a[3] * sc);
    o.z = pk2(a[4] * sc, a[5] * sc); o.w = pk2(a[6] * sc, a[7] * sc);
    outb[(size_t)cd * 16 + lane] = o;
    if (doscale && lane == 0) ssum[cd] = ss;
}

// ======== weight prep, k-split wide kernels ========
__global__ __launch_bounds__(256) void k_wT(
        const float* __restrict__ W2, const float* __restrict__ W3, float* __restrict__ T) {
    int t = threadIdx.x;
    int o = blockIdx.x * 16 + (t >> 4);        // 0..16383
    int sub = t & 15;
    int i = o >> 11, oo = o & 2047;
    int r = oo >> 4, c = oo & 15;
    const float* w2 = W2 + (size_t)i * DD * DD + r * DD + sub * 8;
    const float* w3 = W3 + (size_t)i * DD * DH + c + sub * 8 * DH;
    float acc = 0.f;
    #pragma unroll
    for (int k = 0; k < 8; ++k) acc += w2[k] * w3[k * DH];
    #pragma unroll
    for (int m = 8; m; m >>= 1) acc += __shfl_xor(acc, m);
    if (sub == 0) T[o] = acc;
}

__global__ __launch_bounds__(256) void k_wM(
        const float* __restrict__ W1, const float* __restrict__ T,
        unsigned short* __restrict__ Mtb) {
    int t = threadIdx.x;
    int o = blockIdx.x * 16 + (t >> 4);
    int sub = t & 15;
    int i = o >> 11, oo = o & 2047;
    int r = oo >> 4, c = oo & 15;
    const float* w1 = W1 + (size_t)i * DD * DD + r * DD + sub * 8;
    const float* tt = T + (size_t)i * DD * DH + c + sub * 8 * DH;
    float acc = 0.f;
    #pragma unroll
    for (int k = 0; k < 8; ++k) acc += w1[k] * tt[k * DH];
    #pragma unroll
    for (int m = 8; m; m >>= 1) acc += __shfl_xor(acc, m);
    if (sub == 0) Mtb[(size_t)(i * DH + c) * DD + r] = f2b(acc);
}

__global__ __launch_bounds__(256) void k_cvec2(
        const float* __restrict__ b1, const float* __restrict__ b2,
        const float* __restrict__ T, const float* __restrict__ W3,
        float* __restrict__ cvec) {
    int i = blockIdx.x, t = threadIdx.x;
    int c = t >> 4, sub = t & 15;
    const float* tt = T + (size_t)i * DD * DH + c + sub * 8 * DH;
    const float* w3 = W3 + (size_t)i * DD * DH + c + sub * 8 * DH;
    const float* p1 = b1 + i * DD + sub * 8;
    const float* p2 = b2 + i * DD + sub * 8;
    float acc = 0.f;
    #pragma unroll
    for (int k = 0; k < 8; ++k) acc += p1[k] * tt[k * DH] + p2[k] * w3[k * DH];
    #pragma unroll
    for (int m = 8; m; m >>= 1) acc += __shfl_xor(acc, m);
    if (sub == 0) cvec[i * DH + c] = acc;
}

__global__ void k_wtb2(const float* __restrict__ fW1, const float* __restrict__ fW2,
                       unsigned short* __restrict__ W1tb, unsigned short* __restrict__ W2tb) {
    int idx = blockIdx.x * 256 + threadIdx.x;      // 32768 total
    int which = idx >> 14;
    int o = idx & 16383;
    int c = o >> 7, k = o & 127;
    const float* W = which ? fW2 : fW1;
    unsigned short* Wt = which ? W2tb : W1tb;
    Wt[c * DD + k] = f2b(W[(size_t)k * DD + c]);
}

// ======== fused tail: stage-3 gather + MFMA GEMMs. 64 rows/block, 256 threads ========
// Phase A: gather Q for 128 (graph,row) tasks from Pb (stage-2 output) straight into
// swizzled bf16 LDS panels (identical values/order to the old pull_sumF + staging).
// Phase B: three MFMA GEMMs (unchanged from k_tailm).
__global__ __launch_bounds__(256) void k_tailg(
        const uint4* __restrict__ Pb, const int* __restrict__ rowptr,
        const int* __restrict__ csr,
        const float* __restrict__ ssum, const float* __restrict__ indeg,
        const unsigned short* __restrict__ Mtb, const unsigned short* __restrict__ W1tb,
        const unsigned short* __restrict__ W2tb,
        const float* __restrict__ cvec, const float* __restrict__ b3,
        const float* __restrict__ h, const float* __restrict__ ln_g,
        const float* __restrict__ ln_b, const float* __restrict__ Fb1,
        const float* __restrict__ Fb2, float* __restrict__ out, int N) {
    __shared__ __align__(16) unsigned short A0[64 * DD];   // 16 KB: Qgt -> x panel
    __shared__ __align__(16) unsigned short A1[64 * DD];   // 16 KB: Qat -> f1 panel
    __shared__ __align__(16) unsigned short Bt[DD * DD];   // 32 KB: weight panel [col][k]
    int t = threadIdx.x;
    int w = t >> 6, l = t & 63;
    int lm = l & 15, lk = l >> 4;
    int row0 = blockIdx.x * 64;

    // ---- stage Bt = Mtb first (streaming; overlaps with gather below) ----
    for (int i = t; i < 2048; i += 256) {
        int c = i >> 4, ch = i & 15;
        uint4 v = *(const uint4*)(Mtb + (size_t)c * DD + ch * 8);
        *(uint4*)((char*)Bt + c * 256 + SWZB(c, ch * 16)) = v;
    }

    // ---- phase A: gather 128 tasks (g,r), 16 lanes each ----
    {
        int lane = t & 15, task0 = t >> 4;     // 16 groups
        for (int it = 0; it < 8; ++it) {
            int j = it * 16 + task0;           // 0..127
            int g = j >> 6, r = j & 63;
            int row = row0 + r; if (row >= N) row = N - 1;
            int cd = row + g * N;
            int base = g * N;
            int beg = rowptr[cd], end = rowptr[cd + 1];
            float a[8] = {0.f, 0.f, 0.f, 0.f, 0.f, 0.f, 0.f, 0.f};
            int e = beg;
            int nb = end - e; if (nb > 16) nb = 16;
            int idx = (lane < nb) ? csr[e + lane] : 0;
            while (nb > 0) {
                int en = e + nb;
                int nbn = end - en; if (nbn > 16) nbn = 16;
                int idxn = (lane < nbn) ? csr[en + lane] : 0;
                #pragma unroll 8
                for (int d = 0; d < nb; ++d) {
                    int s = __shfl(idx, d, 16);
                    upacc(Pb[(size_t)(base + s) * 16 + lane], a);
                }
                e = en; nb = nbn; idx = idxn;
            }
            uint4 o;
            o.x = pk2(a[0], a[1]); o.y = pk2(a[2], a[3]);
            o.z = pk2(a[4], a[5]); o.w = pk2(a[6], a[7]);
            unsigned short* P = g ? A1 : A0;
            *(uint4*)((char*)P + r * 256 + SWZB(r, lane * 16)) = o;
        }
    }
    __syncthreads();

    int arow = w * 16 + lm;
    int abase = arow * 256;

    // ---- GEMM1 ----
    f32x4 acc[8];
    #pragma unroll
    for (int i = 0; i < 8; ++i) acc[i] = (f32x4){0.f, 0.f, 0.f, 0.f};
    #pragma unroll
    for (int kt = 0; kt < 4; ++kt) {
        int aoff = abase + SWZB(arow, kt * 64 + lk * 16);
        bf16x8 ag = *(const bf16x8*)((const char*)A0 + aoff);
        bf16x8 aa = *(const bf16x8*)((const char*)A1 + aoff);
        #pragma unroll
        for (int ct = 0; ct < 8; ++ct) {
            int bc = ct * 16 + lm;
            bf16x8 b = *(const bf16x8*)((const char*)Bt + bc * 256 + SWZB(bc, kt * 64 + lk * 16));
            acc[ct] = __builtin_amdgcn_mfma_f32_16x16x32_bf16(
                ((ct >> 1) & 1) ? aa : ag, b, acc[ct], 0, 0, 0);
        }
    }

    // ---- epilogue 1: (acc + ss*c)*nd + b3, LN over 128 cols, + h residual ----
    int rbase = row0 + w * 16 + lk * 4;
    float ssv[2][4], ndv[2][4];
    #pragma unroll
    for (int i = 0; i < 4; ++i) {
        int rc = rbase + i; if (rc >= N) rc = N - 1;
        #pragma unroll
        for (int g2 = 0; g2 < 2; ++g2) {
            ssv[g2][i] = ssum[g2 * N + rc];
            float id = indeg[g2 * N + rc];
            ndv[g2][i] = id > 0.f ? rsqrtf(id) : 0.f;
        }
    }
    float glr[8], blr[8];
    #pragma unroll
    for (int ct = 0; ct < 8; ++ct) {
        glr[ct] = ln_g[ct * 16 + lm];
        blr[ct] = ln_b[ct * 16 + lm];
    }
    float vv[8][4];
    float s[4] = {0, 0, 0, 0}, s2[4] = {0, 0, 0, 0};
    #pragma unroll
    for (int ct = 0; ct < 8; ++ct) {
        int col = ct * 16 + lm;
        int g2 = (ct >> 1) & 1;
        float cvv = cvec[col], b3v = b3[col];
        #pragma unroll
        for (int i = 0; i < 4; ++i) {
            float v = (acc[ct][i] + ssv[g2][i] * cvv) * ndv[g2][i] + b3v;
            vv[ct][i] = v;
            s[i] += v; s2[i] += v * v;
        }
    }
    #pragma unroll
    for (int o = 8; o > 0; o >>= 1) {
        #pragma unroll
        for (int i = 0; i < 4; ++i) {
            s[i] += __shfl_xor(s[i], o);
            s2[i] += __shfl_xor(s2[i], o);
        }
    }
    __syncthreads();                        // all GEMM1 LDS reads done
    float xk[8][4];
    #pragma unroll
    for (int i = 0; i < 4; ++i) {
        float mu = s[i] * (1.f / DD);
        float var = s2[i] * (1.f / DD) - mu * mu;
        float rs = rsqrtf(var + EPS);
        int row = rbase + i; int rc = row < N ? row : N - 1;
        int lrow = w * 16 + lk * 4 + i;
        #pragma unroll
        for (int ct = 0; ct < 8; ++ct) {
            int col = ct * 16 + lm;
            float x = h[(size_t)rc * DD + col] + (vv[ct][i] - mu) * rs * glr[ct] + blr[ct];
            xk[ct][i] = x;
            *(unsigned short*)((char*)A0 + lrow * 256 + SWZB(lrow, 2 * col)) = f2b(x);
        }
    }
    for (int i = t; i < 2048; i += 256) {   // stage Bt = W1tb
        int c = i >> 4, ch = i & 15;
        uint4 v = *(const uint4*)(W1tb + (size_t)c * DD + ch * 8);
        *(uint4*)((char*)Bt + c * 256 + SWZB(c, ch * 16)) = v;
    }
    __syncthreads();

    // ---- GEMM2: f1 = relu(x @ fW1 + Fb1) ----
    f32x4 ac2[8];
    #pragma unroll
    for (int i = 0; i < 8; ++i) ac2[i] = (f32x4){0.f, 0.f, 0.f, 0.f};
    #pragma unroll
    for (int kt = 0; kt < 4; ++kt) {
        bf16x8 a = *(const bf16x8*)((const char*)A0 + abase + SWZB(arow, kt * 64 + lk * 16));
        #pragma unroll
        for (int ct = 0; ct < 8; ++ct) {
            int bc = ct * 16 + lm;
            bf16x8 b = *(const bf16x8*)((const char*)Bt + bc * 256 + SWZB(bc, kt * 64 + lk * 16));
            ac2[ct] = __builtin_amdgcn_mfma_f32_16x16x32_bf16(a, b, ac2[ct], 0, 0, 0);
        }
    }
    #pragma unroll
    for (int i = 0; i < 4; ++i) {
        int lrow = w * 16 + lk * 4 + i;
        #pragma unroll
        for (int ct = 0; ct < 8; ++ct) {
            int col = ct * 16 + lm;
            float f = ac2[ct][i] + Fb1[col];
            *(unsigned short*)((char*)A1 + lrow * 256 + SWZB(lrow, 2 * col)) =
                f2b(f > 0.f ? f : 0.f);
        }
    }
    __syncthreads();                        // GEMM2 Bt reads + f1 writes done
    for (int i = t; i < 2048; i += 256) {   // stage Bt = W2tb
        int c = i >> 4, ch = i & 15;
        uint4 v = *(const uint4*)(W2tb + (size_t)c * DD + ch * 8);
        *(uint4*)((char*)Bt + c * 256 + SWZB(c, ch * 16)) = v;
    }
    __syncthreads();

    // ---- GEMM3: out = x + LN(f1 @ fW2 + Fb2) ----
    f32x4 ac3[8];
    #pragma unroll
    for (int i = 0; i < 8; ++i) ac3[i] = (f32x4){0.f, 0.f, 0.f, 0.f};
    #pragma unroll
    for (int kt = 0; kt < 4; ++kt) {
        bf16x8 a = *(const bf16x8*)((const char*)A1 + abase + SWZB(arow, kt * 64 + lk * 16));
        #pragma unroll
        for (int ct = 0; ct < 8; ++ct) {
            int bc = ct * 16 + lm;
            bf16x8 b = *(const bf16x8*)((const char*)Bt + bc * 256 + SWZB(bc, kt * 64 + lk * 16));
            ac3[ct] = __builtin_amdgcn_mfma_f32_16x16x32_bf16(a, b, ac3[ct], 0, 0, 0);
        }
    }
    float v3[8][4];
    float s3[4] = {0, 0, 0, 0}, s32[4] = {0, 0, 0, 0};
    #pragma unroll
    for (int ct = 0; ct < 8; ++ct) {
        float fb = Fb2[ct * 16 + lm];
        #pragma unroll
        for (int i = 0; i < 4; ++i) {
            float v = ac3[ct][i] + fb;
            v3[ct][i] = v;
            s3[i] += v; s32[i] += v * v;
        }
    }
    #pragma unroll
    for (int o = 8; o > 0; o >>= 1) {
        #pragma unroll
        for (int i = 0; i < 4; ++i) {
            s3[i] += __shfl_xor(s3[i], o);
            s32[i] += __shfl_xor(s32[i], o);
        }
    }
    #pragma unroll
    for (int i = 0; i < 4; ++i) {
        float mu = s3[i] * (1.f / DD);
        float var = s32[i] * (1.f / DD) - mu * mu;
        float rs = rsqrtf(var + EPS);
        int row = rbase + i;
        if (row < N) {
            #pragma unroll
            for (int ct = 0; ct < 8; ++ct) {
                int col = ct * 16 + lm;
                out[(size_t)row * DD + col] = xk[ct][i] + (v3[ct][i] - mu) * rs * glr[ct] + blr[ct];
            }
        }
    }
}

extern "C" void kernel_launch(void* const* d_in, const int* in_sizes, int n_in,
                              void* d_out, int out_size, void* d_ws, size_t ws_size,
                              hipStream_t stream) {
    const float* h      = (const float*)d_in[0];
    const int*   gt_src = (const int*)d_in[1];
    const int*   gt_dst = (const int*)d_in[2];
    const int*   at_src = (const int*)d_in[3];
    const int*   at_dst = (const int*)d_in[4];
    const float* W1     = (const float*)d_in[5];
    const float* b1     = (const float*)d_in[6];
    const float* W2     = (const float*)d_in[7];
    const float* b2     = (const float*)d_in[8];
    const float* W3     = (const float*)d_in[9];
    const float* b3     = (const float*)d_in[10];
    const float* fW1    = (const float*)d_in[11];
    const float* fb1    = (const float*)d_in[12];
    const float* fW2    = (const float*)d_in[13];
    const float* fb2    = (const float*)d_in[14];
    const float* ln_g   = (const float*)d_in[15];
    const float* ln_b   = (const float*)d_in[16];

    const int E = in_sizes[1];
    const int N = in_sizes[0] / DD;
    const size_t NB = (size_t)N * DD;
    const int N2 = 2 * N;
    const int Btot = (N2 + BWIDTH - 1) >> BSH;
    const int n1 = 2 * Btot * NBLK1;

    // ---- workspace layout (combined bf16 tables) ----
    unsigned short* hb   = (unsigned short*)d_ws;          // NB bf16 (12.8 MB)
    unsigned short* bufA = hb + NB;                        // 2*NB bf16 (25.6 MB)
    unsigned short* bufB = bufA + 2 * NB;                  // 2*NB bf16 (25.6 MB)
    float* sm = (float*)(bufB + 2 * NB);
    float* norms = sm;  sm += N2;
    float* indeg = sm;  sm += N2;
    float* ssum  = sm;  sm += N2;
    float* cvec  = sm;  sm += NHEAD * DH + 32;
    float* Tm    = sm;  sm += NHEAD * DD * DH;             // 16384 f32 (64 KB)
    unsigned short* Mtb  = (unsigned short*)sm;
    unsigned short* W1tb = Mtb + DD * DD;
    unsigned short* W2tb = W1tb + DD * DD;
    int* ip = (int*)(W2tb + DD * DD);
    int* rowptr = ip;  ip += ((N2 + 1 + 3) & ~3);
    int* csr    = ip;  ip += 2 * E;
    int* blkcnt = ip;  ip += ((n1 + 1 + 3) & ~3);
    int* scn    = ip;  ip += ((n1 + 1 + 3) & ~3);
    int* part   = ip;  ip += 256;
    // CSR-build scratch aliased over bufA (7.2 MB < 25.6 MB; bufA first written at stage 2)
    unsigned* pairs = (unsigned*)bufA;                     // 2E uint (4.8 MB)
    unsigned short* svals = (unsigned short*)(pairs + 2 * E);  // 2E ushort (2.4 MB)

    // wide k-split weight prep (latency-hidden)
    k_wT   <<<1024, 256, 0, stream>>>(W2, W3, Tm);
    k_wM   <<<1024, 256, 0, stream>>>(W1, Tm, Mtb);
    k_cvec2<<<NHEAD, 256, 0, stream>>>(b1, b2, Tm, W3, cvec);
    k_wtb2 <<<128, 256, 0, stream>>>(fW1, fW2, W1tb, W2tb);

    const int TB = 256;
    // h -> bf16
    k_h2b<<<(int)(NB / 4 + TB - 1) / TB, TB, 0, stream>>>((const float4*)h, (ushort4*)hb,
                                                          (int)(NB / 4));
    // CSR build (no global atomics; packed intermediates)
    k_p1count<<<NBLK1, 256, 0, stream>>>(gt_src, gt_dst, at_src, at_dst, blkcnt, E, N, Btot);
    int nsb = (n1 + 1023) / 1024;
    k_scan1<<<nsb, 256, 0, stream>>>(blkcnt, scn, part, n1);
    k_scan2<<<1, 256, 0, stream>>>(part, nsb);
    k_scan3<<<(n1 + TB - 1) / TB, TB, 0, stream>>>(scn, part, n1, 4 * E);
    k_p1scatter<<<NBLK1, 256, 0, stream>>>(gt_src, gt_dst, at_src, at_dst, scn,
                                           pairs, svals, E, N, Btot);
    k_p2<<<Btot, 256, 0, stream>>>(pairs, svals, scn, rowptr, csr, indeg, norms,
                                   E, N2, Btot);

    // pull stages 1+2 over combined [0,2N)
    const int pgrid2 = (N2 + 15) / 16;
    k_pull_avgF<<<pgrid2, 256, 0, stream>>>((const uint4*)hb, rowptr, csr, norms,
                                            (uint4*)bufB, ssum, N, 1, 0);
    k_pull_avgF<<<pgrid2, 256, 0, stream>>>((const uint4*)bufB, rowptr, csr, norms,
                                            (uint4*)bufA, ssum, N, 0, 1);

    // fused stage-3 gather + dense tail (MFMA bf16, 64 rows/block)
    k_tailg<<<(N + 63) / 64, 256, 0, stream>>>((const uint4*)bufA, rowptr, csr,
                                               ssum, indeg, Mtb, W1tb, W2tb,
                                               cvec, b3, h, ln_g, ln_b, fb1, fb2,
                                               (float*)d_out, N);
}

// Round 17
// 245.951 us; speedup vs baseline: 1.2394x; 1.2394x over previous
//
#include <hip/hip_runtime.h>

#define DD 128
#define NHEAD 8
#define DH 16
#define EPS 1e-5f
#define BSH 9                 // bucket width 512 nodes
#define BWIDTH 512
#define NBLK1 256             // pass-1 blocks

typedef __attribute__((ext_vector_type(8))) short bf16x8;   // 8 bf16 = 4 VGPR
typedef __attribute__((ext_vector_type(4))) float f32x4;

// ---------- bf16 helpers (OCP bf16 = f32 upper half, RNE) ----------
__device__ inline unsigned short f2b(float f) {
    unsigned u = __float_as_uint(f);
    u += 0x7fffu + ((u >> 16) & 1);
    return (unsigned short)(u >> 16);
}
__device__ inline unsigned pk2(float lo, float hi) {
    return (unsigned)f2b(lo) | ((unsigned)f2b(hi) << 16);
}
// unpack-accumulate 8 bf16 (uint4 = 16 B) into a[8]
__device__ inline void upacc(uint4 u, float* a) {
    a[0] += __uint_as_float(u.x << 16);
    a[1] += __uint_as_float(u.x & 0xffff0000u);
    a[2] += __uint_as_float(u.y << 16);
    a[3] += __uint_as_float(u.y & 0xffff0000u);
    a[4] += __uint_as_float(u.z << 16);
    a[5] += __uint_as_float(u.z & 0xffff0000u);
    a[6] += __uint_as_float(u.w << 16);
    a[7] += __uint_as_float(u.w & 0xffff0000u);
}

// XOR swizzle for bf16 MFMA panels (row stride 256 B): keeps 16B alignment.
#define SWZB(row, off) ((off) ^ (((row) & 7) << 4))

// ================= h -> bf16 copy =================
__global__ void k_h2b(const float4* __restrict__ h4, ushort4* __restrict__ hb, int n4) {
    int i = blockIdx.x * 256 + threadIdx.x;
    if (i < n4) {
        float4 v = h4[i];
        hb[i] = make_ushort4(f2b(v.x), f2b(v.y), f2b(v.z), f2b(v.w));
    }
}

// ================= pass 1a: per-block bucket histograms =================
__global__ __launch_bounds__(256) void k_p1count(
        const int* __restrict__ gs, const int* __restrict__ gd,
        const int* __restrict__ as_, const int* __restrict__ ad,
        int* __restrict__ blkcnt, int E, int N, int Btot) {
    __shared__ int cnts[512];
    for (int j = threadIdx.x; j < 2 * Btot; j += 256) cnts[j] = 0;
    __syncthreads();
    int E2 = 2 * E;
    for (int i = blockIdx.x * 256 + threadIdx.x; i < E2; i += NBLK1 * 256) {
        int g = (i >= E);
        int e = g ? i - E : i;
        int s = g ? as_[e] : gs[e];
        int d = g ? ad[e] : gd[e];
        int cd = d + g * N, cs = s + g * N;
        atomicAdd(&cnts[cd >> BSH], 1);
        atomicAdd(&cnts[Btot + (cs >> BSH)], 1);
    }
    __syncthreads();
    for (int j = threadIdx.x; j < 2 * Btot; j += 256)
        blkcnt[j * NBLK1 + blockIdx.x] = cnts[j];
}

// ================= 3-stage scan =================
__global__ void k_scan1(const int* __restrict__ cnt, int* __restrict__ outv,
                        int* __restrict__ part, int n) {
    __shared__ int wsums[4];
    int t = threadIdx.x;
    int base = blockIdx.x * 1024 + t * 4;
    int v0 = 0, v1 = 0, v2 = 0, v3 = 0;
    if (base + 3 < n) {
        int4 q = *(const int4*)(cnt + base);
        v0 = q.x; v1 = q.y; v2 = q.z; v3 = q.w;
    } else {
        if (base < n)     v0 = cnt[base];
        if (base + 1 < n) v1 = cnt[base + 1];
        if (base + 2 < n) v2 = cnt[base + 2];
        if (base + 3 < n) v3 = cnt[base + 3];
    }
    int s0 = v0, s1 = s0 + v1, s2 = s1 + v2, s3 = s2 + v3;
    int x = s3;
    int lane = t & 63, w = t >> 6;
    for (int o = 1; o < 64; o <<= 1) { int u = __shfl_up(x, o); if (lane >= o) x += u; }
    if (lane == 63) wsums[w] = x;
    __syncthreads();
    int wo = 0;
    for (int i = 0; i < w; ++i) wo += wsums[i];
    int excl = wo + x - s3;
    if (base < n)     outv[base]     = excl;
    if (base + 1 < n) outv[base + 1] = excl + s0;
    if (base + 2 < n) outv[base + 2] = excl + s1;
    if (base + 3 < n) outv[base + 3] = excl + s2;
    if (t == 255) part[blockIdx.x] = wo + x;
}

__global__ void k_scan2(int* __restrict__ part, int nb) {
    __shared__ int ws[4];
    int t = threadIdx.x;
    int v = (t < nb) ? part[t] : 0;
    int x = v;
    int lane = t & 63, w = t >> 6;
    for (int o = 1; o < 64; o <<= 1) { int u = __shfl_up(x, o); if (lane >= o) x += u; }
    if (lane == 63) ws[w] = x;
    __syncthreads();
    int wo = 0;
    for (int i = 0; i < w; ++i) wo += ws[i];
    if (t < nb) part[t] = wo + x - v;
}

__global__ void k_scan3(int* __restrict__ outv, const int* __restrict__ part, int n, int total) {
    int i = blockIdx.x * blockDim.x + threadIdx.x;
    if (i < n) outv[i] += part[i >> 10];
    if (i == 0) outv[n] = total;
}

// ======== pass 1b: scatter edges into bucket regions (packed: local_d<<16 | src) ========
// requires N <= 65536 and BWIDTH <= 512 (src 16 bits, local 9 bits)
__global__ __launch_bounds__(256) void k_p1scatter(
        const int* __restrict__ gs, const int* __restrict__ gd,
        const int* __restrict__ as_, const int* __restrict__ ad,
        const int* __restrict__ scn, unsigned* __restrict__ pairs,
        unsigned short* __restrict__ svals, int E, int N, int Btot) {
    __shared__ int cur[512];
    for (int j = threadIdx.x; j < 2 * Btot; j += 256)
        cur[j] = scn[j * NBLK1 + blockIdx.x];
    __syncthreads();
    int E2 = 2 * E;
    for (int i = blockIdx.x * 256 + threadIdx.x; i < E2; i += NBLK1 * 256) {
        int g = (i >= E);
        int e = g ? i - E : i;
        int s = g ? as_[e] : gs[e];
        int d = g ? ad[e] : gd[e];
        int cd = d + g * N, cs = s + g * N;
        int pd = atomicAdd(&cur[cd >> BSH], 1);
        pairs[pd] = ((unsigned)(cd & (BWIDTH - 1)) << 16) | (unsigned)s;
        int ps = atomicAdd(&cur[Btot + (cs >> BSH)], 1);
        svals[ps - E2] = (unsigned short)(cs & (BWIDTH - 1));
    }
}

// ================= pass 2: per-bucket CSR + indeg + norms =================
__global__ __launch_bounds__(256) void k_p2(
        const unsigned* __restrict__ pairs, const unsigned short* __restrict__ svals,
        const int* __restrict__ scn, int* __restrict__ rowptr, int* __restrict__ csr,
        float* __restrict__ indeg, float* __restrict__ norms,
        int E, int N2, int Btot) {
    __shared__ int hist[BWIDTH];
    __shared__ int offs[BWIDTH];
    __shared__ int cur[BWIDTH];
    __shared__ int ws4[4];
    int b = blockIdx.x, t = threadIdx.x;
    int node0 = b << BSH;
    int W = N2 - node0; if (W > BWIDTH) W = BWIDTH;
    int Sd = scn[b * NBLK1], Ed = scn[(b + 1) * NBLK1];
    hist[t] = 0; hist[t + 256] = 0;
    __syncthreads();
    for (int i = Sd + t; i < Ed; i += 256)
        atomicAdd(&hist[pairs[i] >> 16], 1);
    __syncthreads();
    int a0 = hist[2 * t], a1 = hist[2 * t + 1];
    int sum2 = a0 + a1;
    int lane = t & 63, w = t >> 6;
    int x = sum2;
    for (int o = 1; o < 64; o <<= 1) { int u = __shfl_up(x, o); if (lane >= o) x += u; }
    if (lane == 63) ws4[w] = x;
    __syncthreads();
    int wo = 0;
    for (int i = 0; i < w; ++i) wo += ws4[i];
    int excl2 = wo + x - sum2;
    offs[2 * t] = excl2; offs[2 * t + 1] = excl2 + a0;
    cur[t] = 0; cur[t + 256] = 0;
    __syncthreads();
    for (int j = t; j < W; j += 256) {
        rowptr[node0 + j] = Sd + offs[j];
        indeg[node0 + j] = (float)hist[j];
    }
    if (b == 0 && t == 0) rowptr[N2] = 2 * E;
    for (int i = Sd + t; i < Ed; i += 256) {
        unsigned p = pairs[i];
        int l = p >> 16;
        int pos = atomicAdd(&cur[l], 1);
        csr[Sd + offs[l] + pos] = (int)(p & 0xffffu);
    }
    __syncthreads();
    hist[t] = 0; hist[t + 256] = 0;
    __syncthreads();
    int Ss = scn[(Btot + b) * NBLK1] - 2 * E;
    int Es = scn[(Btot + b + 1) * NBLK1] - 2 * E;
    for (int i = Ss + t; i < Es; i += 256)
        atomicAdd(&hist[svals[i]], 1);
    __syncthreads();
    for (int j = t; j < W; j += 256) {
        int od = hist[j];
        norms[node0 + j] = od > 0 ? rsqrtf((float)od) : 0.f;
    }
}

// ======== fused pull stage 1/2: avg (SAGE); 16 lanes/row, uint4 loads ========
__global__ __launch_bounds__(256) void k_pull_avgF(
        const uint4* __restrict__ xb, const int* __restrict__ rowptr,
        const int* __restrict__ csr, const float* __restrict__ norms,
        uint4* __restrict__ outb, float* __restrict__ ssum,
        int N, int shared_in, int doscale) {
    int cd = blockIdx.x * 16 + (threadIdx.x >> 4);
    int lane = threadIdx.x & 15;
    if (cd >= 2 * N) return;
    int gofs = (cd >= N) ? N : 0;
    int base = shared_in ? 0 : gofs;
    int beg = rowptr[cd], end = rowptr[cd + 1];
    float a[8];
    {
        uint4 u = xb[(size_t)(base + cd - gofs) * 16 + lane];   // self term
        a[0] = __uint_as_float(u.x << 16); a[1] = __uint_as_float(u.x & 0xffff0000u);
        a[2] = __uint_as_float(u.y << 16); a[3] = __uint_as_float(u.y & 0xffff0000u);
        a[4] = __uint_as_float(u.z << 16); a[5] = __uint_as_float(u.z & 0xffff0000u);
        a[6] = __uint_as_float(u.w << 16); a[7] = __uint_as_float(u.w & 0xffff0000u);
    }
    float ss = 0.f;
    int e = beg;
    int nb = end - e; if (nb > 16) nb = 16;
    int idx = (lane < nb) ? csr[e + lane] : 0;
    while (nb > 0) {
        int en = e + nb;
        int nbn = end - en; if (nbn > 16) nbn = 16;
        int idxn = (lane < nbn) ? csr[en + lane] : 0;           // prefetch next chunk
        #pragma unroll 8
        for (int d = 0; d < nb; ++d) {
            int s = __shfl(idx, d, 16);
            upacc(xb[(size_t)(base + s) * 16 + lane], a);
            if (doscale) ss += norms[base + s];
        }
        e = en; nb = nbn; idx = idxn;
    }
    float sc = 1.f / (float)(end - beg + 1);
    if (doscale) sc *= norms[cd];
    uint4 o;
    o.x = pk2(a[0] * sc, a[1] * sc); o.y = pk2(a[2] * sc, a[3] * sc);
    o.z = pk2(a[4] * sc, a[5] * sc); o.w = pk2(a[6] * sc, a[7] * sc);
    outb[(size_t)cd * 16 + lane] = o;
    if (doscale && lane == 0) ssum[cd] = ss;
}

// ======== fused pull stage 3: plain sum of pre-scaled rows -> bf16 Q (combined) ========
__global__ __launch_bounds__(256) void k_pull_sumF(
        const uint4* __restrict__ Pb, const int* __restrict__ rowptr,
        const int* __restrict__ csr, uint4* __restrict__ Qb, int N) {
    int cd = blockIdx.x * 16 + (threadIdx.x >> 4);
    int lane = threadIdx.x & 15;
    if (cd >= 2 * N) return;
    int base = (cd >= N) ? N : 0;
    int beg = rowptr[cd], end = rowptr[cd + 1];
    float a[8] = {0.f, 0.f, 0.f, 0.f, 0.f, 0.f, 0.f, 0.f};
    int e = beg;
    int nb = end - e; if (nb > 16) nb = 16;
    int idx = (lane < nb) ? csr[e + lane] : 0;
    while (nb > 0) {
        int en = e + nb;
        int nbn = end - en; if (nbn > 16) nbn = 16;
        int idxn = (lane < nbn) ? csr[en + lane] : 0;
        #pragma unroll 8
        for (int d = 0; d < nb; ++d) {
            int s = __shfl(idx, d, 16);
            upacc(Pb[(size_t)(base + s) * 16 + lane], a);
        }
        e = en; nb = nbn; idx = idxn;
    }
    uint4 o;
    o.x = pk2(a[0], a[1]); o.y = pk2(a[2], a[3]);
    o.z = pk2(a[4], a[5]); o.w = pk2(a[6], a[7]);
    Qb[(size_t)cd * 16 + lane] = o;
}

// ======== weight prep, k-split wide kernels ========
__global__ __launch_bounds__(256) void k_wT(
        const float* __restrict__ W2, const float* __restrict__ W3, float* __restrict__ T) {
    int t = threadIdx.x;
    int o = blockIdx.x * 16 + (t >> 4);        // 0..16383
    int sub = t & 15;
    int i = o >> 11, oo = o & 2047;
    int r = oo >> 4, c = oo & 15;
    const float* w2 = W2 + (size_t)i * DD * DD + r * DD + sub * 8;
    const float* w3 = W3 + (size_t)i * DD * DH + c + sub * 8 * DH;
    float acc = 0.f;
    #pragma unroll
    for (int k = 0; k < 8; ++k) acc += w2[k] * w3[k * DH];
    #pragma unroll
    for (int m = 8; m; m >>= 1) acc += __shfl_xor(acc, m);
    if (sub == 0) T[o] = acc;
}

__global__ __launch_bounds__(256) void k_wM(
        const float* __restrict__ W1, const float* __restrict__ T,
        unsigned short* __restrict__ Mtb) {
    int t = threadIdx.x;
    int o = blockIdx.x * 16 + (t >> 4);
    int sub = t & 15;
    int i = o >> 11, oo = o & 2047;
    int r = oo >> 4, c = oo & 15;
    const float* w1 = W1 + (size_t)i * DD * DD + r * DD + sub * 8;
    const float* tt = T + (size_t)i * DD * DH + c + sub * 8 * DH;
    float acc = 0.f;
    #pragma unroll
    for (int k = 0; k < 8; ++k) acc += w1[k] * tt[k * DH];
    #pragma unroll
    for (int m = 8; m; m >>= 1) acc += __shfl_xor(acc, m);
    if (sub == 0) Mtb[(size_t)(i * DH + c) * DD + r] = f2b(acc);
}

__global__ __launch_bounds__(256) void k_cvec2(
        const float* __restrict__ b1, const float* __restrict__ b2,
        const float* __restrict__ T, const float* __restrict__ W3,
        float* __restrict__ cvec) {
    int i = blockIdx.x, t = threadIdx.x;
    int c = t >> 4, sub = t & 15;
    const float* tt = T + (size_t)i * DD * DH + c + sub * 8 * DH;
    const float* w3 = W3 + (size_t)i * DD * DH + c + sub * 8 * DH;
    const float* p1 = b1 + i * DD + sub * 8;
    const float* p2 = b2 + i * DD + sub * 8;
    float acc = 0.f;
    #pragma unroll
    for (int k = 0; k < 8; ++k) acc += p1[k] * tt[k * DH] + p2[k] * w3[k * DH];
    #pragma unroll
    for (int m = 8; m; m >>= 1) acc += __shfl_xor(acc, m);
    if (sub == 0) cvec[i * DH + c] = acc;
}

__global__ void k_wtb2(const float* __restrict__ fW1, const float* __restrict__ fW2,
                       unsigned short* __restrict__ W1tb, unsigned short* __restrict__ W2tb) {
    int idx = blockIdx.x * 256 + threadIdx.x;      // 32768 total
    int which = idx >> 14;
    int o = idx & 16383;
    int c = o >> 7, k = o & 127;
    const float* W = which ? fW2 : fW1;
    unsigned short* Wt = which ? W2tb : W1tb;
    Wt[c * DD + k] = f2b(W[(size_t)k * DD + c]);
}

// ================= fused tail, MFMA bf16: 64 rows/block, 4 waves =================
__global__ __launch_bounds__(256) void k_tailm(
        const unsigned short* __restrict__ Qgtb, const unsigned short* __restrict__ Qatb,
        const float* __restrict__ ssum, const float* __restrict__ indeg,
        const unsigned short* __restrict__ Mtb, const unsigned short* __restrict__ W1tb,
        const unsigned short* __restrict__ W2tb,
        const float* __restrict__ cvec, const float* __restrict__ b3,
        const float* __restrict__ h, const float* __restrict__ ln_g,
        const float* __restrict__ ln_b, const float* __restrict__ Fb1,
        const float* __restrict__ Fb2, float* __restrict__ out, int N) {
    __shared__ __align__(16) unsigned short A0[64 * DD];   // 16 KB: Qgt -> x panel
    __shared__ __align__(16) unsigned short A1[64 * DD];   // 16 KB: Qat -> f1 panel
    __shared__ __align__(16) unsigned short Bt[DD * DD];   // 32 KB: weight panel [col][k]
    int t = threadIdx.x;
    int w = t >> 6, l = t & 63;
    int lm = l & 15, lk = l >> 4;
    int row0 = blockIdx.x * 64;

    // ---- stage A panels (Q bf16, swizzled) ----
    for (int i = t; i < 1024; i += 256) {
        int r = i >> 4, ch = i & 15;
        int gr = row0 + r; if (gr >= N) gr = N - 1;
        uint4 v0 = *(const uint4*)(Qgtb + (size_t)gr * DD + ch * 8);
        uint4 v1 = *(const uint4*)(Qatb + (size_t)gr * DD + ch * 8);
        *(uint4*)((char*)A0 + r * 256 + SWZB(r, ch * 16)) = v0;
        *(uint4*)((char*)A1 + r * 256 + SWZB(r, ch * 16)) = v1;
    }
    // ---- stage Bt = Mtb ----
    for (int i = t; i < 2048; i += 256) {
        int c = i >> 4, ch = i & 15;
        uint4 v = *(const uint4*)(Mtb + (size_t)c * DD + ch * 8);
        *(uint4*)((char*)Bt + c * 256 + SWZB(c, ch * 16)) = v;
    }
    __syncthreads();

    int arow = w * 16 + lm;
    int abase = arow * 256;

    // ---- GEMM1 ----
    f32x4 acc[8];
    #pragma unroll
    for (int i = 0; i < 8; ++i) acc[i] = (f32x4){0.f, 0.f, 0.f, 0.f};
    #pragma unroll
    for (int kt = 0; kt < 4; ++kt) {
        int aoff = abase + SWZB(arow, kt * 64 + lk * 16);
        bf16x8 ag = *(const bf16x8*)((const char*)A0 + aoff);
        bf16x8 aa = *(const bf16x8*)((const char*)A1 + aoff);
        #pragma unroll
        for (int ct = 0; ct < 8; ++ct) {
            int bc = ct * 16 + lm;
            bf16x8 b = *(const bf16x8*)((const char*)Bt + bc * 256 + SWZB(bc, kt * 64 + lk * 16));
            acc[ct] = __builtin_amdgcn_mfma_f32_16x16x32_bf16(
                ((ct >> 1) & 1) ? aa : ag, b, acc[ct], 0, 0, 0);
        }
    }

    // ---- epilogue 1: (acc + ss*c)*nd + b3, LN over 128 cols, + h residual ----
    int rbase = row0 + w * 16 + lk * 4;
    float ssv[2][4], ndv[2][4];
    #pragma unroll
    for (int i = 0; i < 4; ++i) {
        int rc = rbase + i; if (rc >= N) rc = N - 1;
        #pragma unroll
        for (int g2 = 0; g2 < 2; ++g2) {
            ssv[g2][i] = ssum[g2 * N + rc];
            float id = indeg[g2 * N + rc];
            ndv[g2][i] = id > 0.f ? rsqrtf(id) : 0.f;
        }
    }
    float glr[8], blr[8];
    #pragma unroll
    for (int ct = 0; ct < 8; ++ct) {
        glr[ct] = ln_g[ct * 16 + lm];
        blr[ct] = ln_b[ct * 16 + lm];
    }
    float vv[8][4];
    float s[4] = {0, 0, 0, 0}, s2[4] = {0, 0, 0, 0};
    #pragma unroll
    for (int ct = 0; ct < 8; ++ct) {
        int col = ct * 16 + lm;
        int g2 = (ct >> 1) & 1;
        float cvv = cvec[col], b3v = b3[col];
        #pragma unroll
        for (int i = 0; i < 4; ++i) {
            float v = (acc[ct][i] + ssv[g2][i] * cvv) * ndv[g2][i] + b3v;
            vv[ct][i] = v;
            s[i] += v; s2[i] += v * v;
        }
    }
    #pragma unroll
    for (int o = 8; o > 0; o >>= 1) {
        #pragma unroll
        for (int i = 0; i < 4; ++i) {
            s[i] += __shfl_xor(s[i], o);
            s2[i] += __shfl_xor(s2[i], o);
        }
    }
    __syncthreads();                        // all GEMM1 LDS reads done
    float xk[8][4];
    #pragma unroll
    for (int i = 0; i < 4; ++i) {
        float mu = s[i] * (1.f / DD);
        float var = s2[i] * (1.f / DD) - mu * mu;
        float rs = rsqrtf(var + EPS);
        int row = rbase + i; int rc = row < N ? row : N - 1;
        int lrow = w * 16 + lk * 4 + i;
        #pragma unroll
        for (int ct = 0; ct < 8; ++ct) {
            int col = ct * 16 + lm;
            float x = h[(size_t)rc * DD + col] + (vv[ct][i] - mu) * rs * glr[ct] + blr[ct];
            xk[ct][i] = x;
            *(unsigned short*)((char*)A0 + lrow * 256 + SWZB(lrow, 2 * col)) = f2b(x);
        }
    }
    for (int i = t; i < 2048; i += 256) {   // stage Bt = W1tb
        int c = i >> 4, ch = i & 15;
        uint4 v = *(const uint4*)(W1tb + (size_t)c * DD + ch * 8);
        *(uint4*)((char*)Bt + c * 256 + SWZB(c, ch * 16)) = v;
    }
    __syncthreads();

    // ---- GEMM2: f1 = relu(x @ fW1 + Fb1) ----
    f32x4 ac2[8];
    #pragma unroll
    for (int i = 0; i < 8; ++i) ac2[i] = (f32x4){0.f, 0.f, 0.f, 0.f};
    #pragma unroll
    for (int kt = 0; kt < 4; ++kt) {
        bf16x8 a = *(const bf16x8*)((const char*)A0 + abase + SWZB(arow, kt * 64 + lk * 16));
        #pragma unroll
        for (int ct = 0; ct < 8; ++ct) {
            int bc = ct * 16 + lm;
            bf16x8 b = *(const bf16x8*)((const char*)Bt + bc * 256 + SWZB(bc, kt * 64 + lk * 16));
            ac2[ct] = __builtin_amdgcn_mfma_f32_16x16x32_bf16(a, b, ac2[ct], 0, 0, 0);
        }
    }
    #pragma unroll
    for (int i = 0; i < 4; ++i) {
        int lrow = w * 16 + lk * 4 + i;
        #pragma unroll
        for (int ct = 0; ct < 8; ++ct) {
            int col = ct * 16 + lm;
            float f = ac2[ct][i] + Fb1[col];
            *(unsigned short*)((char*)A1 + lrow * 256 + SWZB(lrow, 2 * col)) =
                f2b(f > 0.f ? f : 0.f);
        }
    }
    __syncthreads();                        // GEMM2 Bt reads + f1 writes done
    for (int i = t; i < 2048; i += 256) {   // stage Bt = W2tb
        int c = i >> 4, ch = i & 15;
        uint4 v = *(const uint4*)(W2tb + (size_t)c * DD + ch * 8);
        *(uint4*)((char*)Bt + c * 256 + SWZB(c, ch * 16)) = v;
    }
    __syncthreads();

    // ---- GEMM3: out = x + LN(f1 @ fW2 + Fb2) ----
    f32x4 ac3[8];
    #pragma unroll
    for (int i = 0; i < 8; ++i) ac3[i] = (f32x4){0.f, 0.f, 0.f, 0.f};
    #pragma unroll
    for (int kt = 0; kt < 4; ++kt) {
        bf16x8 a = *(const bf16x8*)((const char*)A1 + abase + SWZB(arow, kt * 64 + lk * 16));
        #pragma unroll
        for (int ct = 0; ct < 8; ++ct) {
            int bc = ct * 16 + lm;
            bf16x8 b = *(const bf16x8*)((const char*)Bt + bc * 256 + SWZB(bc, kt * 64 + lk * 16));
            ac3[ct] = __builtin_amdgcn_mfma_f32_16x16x32_bf16(a, b, ac3[ct], 0, 0, 0);
        }
    }
    float v3[8][4];
    float s3[4] = {0, 0, 0, 0}, s32[4] = {0, 0, 0, 0};
    #pragma unroll
    for (int ct = 0; ct < 8; ++ct) {
        float fb = Fb2[ct * 16 + lm];
        #pragma unroll
        for (int i = 0; i < 4; ++i) {
            float v = ac3[ct][i] + fb;
            v3[ct][i] = v;
            s3[i] += v; s32[i] += v * v;
        }
    }
    #pragma unroll
    for (int o = 8; o > 0; o >>= 1) {
        #pragma unroll
        for (int i = 0; i < 4; ++i) {
            s3[i] += __shfl_xor(s3[i], o);
            s32[i] += __shfl_xor(s32[i], o);
        }
    }
    #pragma unroll
    for (int i = 0; i < 4; ++i) {
        float mu = s3[i] * (1.f / DD);
        float var = s32[i] * (1.f / DD) - mu * mu;
        float rs = rsqrtf(var + EPS);
        int row = rbase + i;
        if (row < N) {
            #pragma unroll
            for (int ct = 0; ct < 8; ++ct) {
                int col = ct * 16 + lm;
                out[(size_t)row * DD + col] = xk[ct][i] + (v3[ct][i] - mu) * rs * glr[ct] + blr[ct];
            }
        }
    }
}

extern "C" void kernel_launch(void* const* d_in, const int* in_sizes, int n_in,
                              void* d_out, int out_size, void* d_ws, size_t ws_size,
                              hipStream_t stream) {
    const float* h      = (const float*)d_in[0];
    const int*   gt_src = (const int*)d_in[1];
    const int*   gt_dst = (const int*)d_in[2];
    const int*   at_src = (const int*)d_in[3];
    const int*   at_dst = (const int*)d_in[4];
    const float* W1     = (const float*)d_in[5];
    const float* b1     = (const float*)d_in[6];
    const float* W2     = (const float*)d_in[7];
    const float* b2     = (const float*)d_in[8];
    const float* W3     = (const float*)d_in[9];
    const float* b3     = (const float*)d_in[10];
    const float* fW1    = (const float*)d_in[11];
    const float* fb1    = (const float*)d_in[12];
    const float* fW2    = (const float*)d_in[13];
    const float* fb2    = (const float*)d_in[14];
    const float* ln_g   = (const float*)d_in[15];
    const float* ln_b   = (const float*)d_in[16];

    const int E = in_sizes[1];
    const int N = in_sizes[0] / DD;
    const size_t NB = (size_t)N * DD;
    const int N2 = 2 * N;
    const int Btot = (N2 + BWIDTH - 1) >> BSH;
    const int n1 = 2 * Btot * NBLK1;

    // ---- workspace layout (combined bf16 tables) ----
    unsigned short* hb   = (unsigned short*)d_ws;          // NB bf16 (12.8 MB)
    unsigned short* bufA = hb + NB;                        // 2*NB bf16 (25.6 MB)
    unsigned short* bufB = bufA + 2 * NB;                  // 2*NB bf16 (25.6 MB)
    float* sm = (float*)(bufB + 2 * NB);
    float* norms = sm;  sm += N2;
    float* indeg = sm;  sm += N2;
    float* ssum  = sm;  sm += N2;
    float* cvec  = sm;  sm += NHEAD * DH + 32;
    float* Tm    = sm;  sm += NHEAD * DD * DH;             // 16384 f32 (64 KB)
    unsigned short* Mtb  = (unsigned short*)sm;
    unsigned short* W1tb = Mtb + DD * DD;
    unsigned short* W2tb = W1tb + DD * DD;
    int* ip = (int*)(W2tb + DD * DD);
    int* rowptr = ip;  ip += ((N2 + 1 + 3) & ~3);
    int* csr    = ip;  ip += 2 * E;
    int* blkcnt = ip;  ip += ((n1 + 1 + 3) & ~3);
    int* scn    = ip;  ip += ((n1 + 1 + 3) & ~3);
    int* part   = ip;  ip += 256;
    // CSR-build scratch aliased over bufA (7.2 MB < 25.6 MB; bufA first written at stage 2)
    unsigned* pairs = (unsigned*)bufA;                     // 2E uint (4.8 MB)
    unsigned short* svals = (unsigned short*)(pairs + 2 * E);  // 2E ushort (2.4 MB)

    // wide k-split weight prep (latency-hidden)
    k_wT   <<<1024, 256, 0, stream>>>(W2, W3, Tm);
    k_wM   <<<1024, 256, 0, stream>>>(W1, Tm, Mtb);
    k_cvec2<<<NHEAD, 256, 0, stream>>>(b1, b2, Tm, W3, cvec);
    k_wtb2 <<<128, 256, 0, stream>>>(fW1, fW2, W1tb, W2tb);

    const int TB = 256;
    // h -> bf16
    k_h2b<<<(int)(NB / 4 + TB - 1) / TB, TB, 0, stream>>>((const float4*)h, (ushort4*)hb,
                                                          (int)(NB / 4));
    // CSR build (no global atomics; packed intermediates)
    k_p1count<<<NBLK1, 256, 0, stream>>>(gt_src, gt_dst, at_src, at_dst, blkcnt, E, N, Btot);
    int nsb = (n1 + 1023) / 1024;
    k_scan1<<<nsb, 256, 0, stream>>>(blkcnt, scn, part, n1);
    k_scan2<<<1, 256, 0, stream>>>(part, nsb);
    k_scan3<<<(n1 + TB - 1) / TB, TB, 0, stream>>>(scn, part, n1, 4 * E);
    k_p1scatter<<<NBLK1, 256, 0, stream>>>(gt_src, gt_dst, at_src, at_dst, scn,
                                           pairs, svals, E, N, Btot);
    k_p2<<<Btot, 256, 0, stream>>>(pairs, svals, scn, rowptr, csr, indeg, norms,
                                   E, N2, Btot);

    // fused pull stages over combined [0,2N): 3 launches, 16 lanes/row uint4
    const int pgrid2 = (N2 + 15) / 16;
    k_pull_avgF<<<pgrid2, 256, 0, stream>>>((const uint4*)hb, rowptr, csr, norms,
                                            (uint4*)bufB, ssum, N, 1, 0);
    k_pull_avgF<<<pgrid2, 256, 0, stream>>>((const uint4*)bufB, rowptr, csr, norms,
                                            (uint4*)bufA, ssum, N, 0, 1);
    k_pull_sumF<<<pgrid2, 256, 0, stream>>>((const uint4*)bufA, rowptr, csr,
                                            (uint4*)bufB, N);
    unsigned short* Qb = bufB;

    // fused dense tail (MFMA bf16, 64 rows/block, 256 threads)
    k_tailm<<<(N + 63) / 64, 256, 0, stream>>>(Qb, Qb + NB, ssum, indeg, Mtb, W1tb, W2tb,
                                               cvec, b3, h, ln_g, ln_b, fb1, fb2,
                                               (float*)d_out, N);
}